// Round 8
// baseline (281.812 us; speedup 1.0000x reference)
//
#include <hip/hip_runtime.h>
#include <hip/hip_bf16.h>

#define BB 4
#define CC 256
#define NN 4096
#define GG 8
#define SPLITS 4
#define TKV 32
#define ITERS (NN / SPLITS / TKV)

typedef unsigned short u16;
typedef unsigned int u32;
typedef __bf16 b16x8 __attribute__((ext_vector_type(8)));
typedef float f32x4 __attribute__((ext_vector_type(4)));
typedef u32 u32x4 __attribute__((ext_vector_type(4)));
typedef u32 u32x2 __attribute__((ext_vector_type(2)));
typedef u16 u16x4 __attribute__((ext_vector_type(4)));

// Q pre-scale: C^-0.5 * log2(e) so softmax runs in exp2 domain
#define QSCALE 0.09016844005556021f
#define FMAX 16.0f

// fragment-major chunk: 512 u16 elems = 16 rows x 32 cols in MFMA lane order.
// elem(row, col32) = (quad(col32>>3)*16 + (row&15))*8 + (col32&7)
// A-read gives A[m=row][k=col]; B-read gives B[k=col][n=row].

__device__ __forceinline__ u16 f2bf(float f) {
    u32 u = __builtin_bit_cast(u32, f);
    u = (u + 0x7FFFu + ((u >> 16) & 1u)) >> 16;
    return (u16)u;
}

__device__ __forceinline__ float bf2f(u16 h) {
    return __builtin_bit_cast(float, (u32)h << 16);
}

__device__ __forceinline__ u32 pack_bf2(float a, float b) {
    float2 f; f.x = a; f.y = b;
    __hip_bfloat162 h = __float22bfloat162_rn(f);
    u32 r;
    __builtin_memcpy(&r, &h, 4);
    return r;
}

__device__ __forceinline__ float exp2_raw(float x) {
#if __has_builtin(__builtin_amdgcn_exp2f)
    return __builtin_amdgcn_exp2f(x);
#else
    float r;
    asm("v_exp_f32 %0, %1" : "=v"(r) : "v"(x));
    return r;
#endif
}

__device__ __forceinline__ b16x8 ldfrag(const u16* p) {
    u32x4 v = *reinterpret_cast<const u32x4*>(p);
    return __builtin_bit_cast(b16x8, v);
}

// ------- 2. Fold GN into QKV weights (frag-major) + frag-major w_proj -------
__global__ void fold_w(const float* __restrict__ w_qkv, const float* __restrict__ w_proj,
                       const float* __restrict__ gamma, const float* __restrict__ beta,
                       const float* __restrict__ stats,
                       u16* __restrict__ wqf, float* __restrict__ biasq,
                       u16* __restrict__ wpf) {
    int o = blockIdx.x;        // 0..767
    int b = blockIdx.y;        // 0..3
    int c = threadIdx.x;       // 0..255
    int g = c >> 5;
    float mu   = stats[(b * GG + g) * 2];
    float rstd = stats[(b * GG + g) * 2 + 1];
    float a  = gamma[c] * rstd;
    float bb = beta[c] - mu * a;
    float w = w_qkv[o * CC + c];
    size_t fe = ((size_t)((o >> 4) * 8 + (c >> 5)) * 64 + ((c & 31) >> 3) * 16 + (o & 15)) * 8 + (c & 7);
    wqf[(size_t)b * 768 * CC + fe] = f2bf(w * a);
    float part = w * bb;
    #pragma unroll
    for (int off = 32; off; off >>= 1) part += __shfl_down(part, off, 64);
    __shared__ float red[4];
    if ((threadIdx.x & 63) == 0) red[threadIdx.x >> 6] = part;
    __syncthreads();
    if (threadIdx.x == 0) biasq[b * 768 + o] = red[0] + red[1] + red[2] + red[3];
    if (b == 0 && o < CC) {
        float wp = w_proj[o * CC + c];
        wpf[fe] = f2bf(wp);
    }
}

// ---- 3. x [B][C][N] fp32 -> xt_frag; fused GroupNorm partial sums ----
__global__ void transpose_x(const float* __restrict__ x, u16* __restrict__ xtf,
                            float* __restrict__ gsum) {
    __shared__ float tile[64][65];
    __shared__ float red[4][4];
    int n0 = blockIdx.x * 64, c0 = blockIdx.y * 64, b = blockIdx.z;
    int t = threadIdx.x;
    int col = t & 63, r0 = t >> 6;
    const float* xp = x + (size_t)b * CC * NN;
    float s0 = 0.f, ss0 = 0.f, s1 = 0.f, ss1 = 0.f;
    #pragma unroll
    for (int i = 0; i < 16; ++i) {
        int row = i * 4 + r0;
        float v = xp[(size_t)(c0 + row) * NN + n0 + col];
        tile[row][col] = v;
        if (i < 8) { s0 += v; ss0 += v * v; } else { s1 += v; ss1 += v * v; }
    }
    #pragma unroll
    for (int off = 32; off; off >>= 1) {
        s0 += __shfl_down(s0, off, 64); ss0 += __shfl_down(ss0, off, 64);
        s1 += __shfl_down(s1, off, 64); ss1 += __shfl_down(ss1, off, 64);
    }
    int wid = t >> 6;
    if ((t & 63) == 0) { red[wid][0] = s0; red[wid][1] = ss0; red[wid][2] = s1; red[wid][3] = ss1; }
    __syncthreads();
    if (t < 2) {
        float s  = red[0][t * 2] + red[1][t * 2] + red[2][t * 2] + red[3][t * 2];
        float ss = red[0][t * 2 + 1] + red[1][t * 2 + 1] + red[2][t * 2 + 1] + red[3][t * 2 + 1];
        int g = (c0 >> 5) + t;
        atomicAdd(&gsum[(b * GG + g) * 2], s);
        atomicAdd(&gsum[(b * GG + g) * 2 + 1], ss);
    }
    int nl = t >> 2;
    int cbq = t & 3;
    int l15 = nl & 15;
    int ntile = (n0 >> 4) + (nl >> 4);
    int kk = (c0 >> 5) + (cbq >> 1);
    u16* ob = xtf + (size_t)b * NN * CC;
    #pragma unroll
    for (int g = 0; g < 4; ++g) {
        int quad = (cbq & 1) * 2 + (g >> 1);
        int j0 = (g & 1) * 4;
        u16x4 v;
        v.x = f2bf(tile[cbq * 16 + g * 4 + 0][nl]);
        v.y = f2bf(tile[cbq * 16 + g * 4 + 1][nl]);
        v.z = f2bf(tile[cbq * 16 + g * 4 + 2][nl]);
        v.w = f2bf(tile[cbq * 16 + g * 4 + 3][nl]);
        *reinterpret_cast<u16x4*>(ob + ((size_t)(ntile * 8 + kk) * 64 + quad * 16 + l15) * 8 + j0) = v;
    }
}

// ---------------- 3b. finalize GN stats ----------------
__global__ void gn_finalize(const float* __restrict__ gsum, float* __restrict__ stats) {
    int i = threadIdx.x;
    if (i < BB * GG) {
        float s = gsum[i * 2], ss = gsum[i * 2 + 1];
        const float inv = 1.f / ((CC / GG) * NN);
        float mu = s * inv;
        float var = ss * inv - mu * mu;
        stats[i * 2] = mu;
        stats[i * 2 + 1] = rsqrtf(var + 1e-5f);
    }
}

// ------- 4. QKV GEMM -> qt_frag, kt_frag (N rows x C cols), v_frag (C rows x N cols) -------
__global__ void __launch_bounds__(256) qkv_gemm(const u16* __restrict__ wqf,
                                                const float* __restrict__ biasq,
                                                const u16* __restrict__ xtf,
                                                u16* __restrict__ qtf, u16* __restrict__ ktf,
                                                u16* __restrict__ vvf) {
    int b = blockIdx.z;
    int o0 = blockIdx.y * 64;
    int n0 = blockIdx.x * 64;
    int lane = threadIdx.x & 63, w = threadIdx.x >> 6;
    int l15 = lane & 15, quad = lane >> 4;
    const u16* A  = wqf + (size_t)b * 768 * CC;
    const u16* Bp = xtf + (size_t)b * NN * CC;
    int otile = (o0 >> 4) + w;
    f32x4 acc[4] = {};
    #pragma unroll
    for (int kk = 0; kk < 8; ++kk) {
        b16x8 af = ldfrag(A + (size_t)(otile * 8 + kk) * 512 + lane * 8);
        #pragma unroll
        for (int nt = 0; nt < 4; ++nt) {
            b16x8 bf = ldfrag(Bp + (size_t)(((n0 >> 4) + nt) * 8 + kk) * 512 + lane * 8);
            acc[nt] = __builtin_amdgcn_mfma_f32_16x16x32_bf16(af, bf, acc[nt], 0, 0, 0);
        }
    }
    int o_base = o0 + w * 16 + quad * 4;
    float bias[4];
    #pragma unroll
    for (int r = 0; r < 4; ++r) bias[r] = biasq[b * 768 + o_base + r];

    if (o0 < 512) {
        int oloc = (o0 < 256) ? o0 : (o0 - 256);
        int kk = (oloc >> 5) + (w >> 1);
        int q_t = (w & 1) * 2 + (quad >> 1);
        int j0 = (quad & 1) * 4;
        u16* dst = ((o0 < 256) ? qtf : ktf) + (size_t)b * NN * CC;
        float sc = (o0 < 256) ? QSCALE : 1.0f;
        #pragma unroll
        for (int nt = 0; nt < 4; ++nt) {
            int n = n0 + nt * 16 + l15;
            int ntile = n >> 4;
            u16x4 pk;
            pk.x = f2bf((acc[nt][0] + bias[0]) * sc);
            pk.y = f2bf((acc[nt][1] + bias[1]) * sc);
            pk.z = f2bf((acc[nt][2] + bias[2]) * sc);
            pk.w = f2bf((acc[nt][3] + bias[3]) * sc);
            *reinterpret_cast<u16x4*>(dst + ((size_t)(ntile * 8 + kk) * 64 + q_t * 16 + l15) * 8 + j0) = pk;
        }
    } else {
        int ctile = ((o0 - 512) + w * 16) >> 4;
        u16* dst = vvf + (size_t)b * NN * CC;
        int jv = l15 & 7;
        #pragma unroll
        for (int nt = 0; nt < 4; ++nt) {
            int kkv = (n0 >> 5) + (nt >> 1);
            int q_v = (nt * 2 + (l15 >> 3)) & 3;
            size_t cb = (size_t)(ctile * (NN / 32) + kkv) * 512;
            #pragma unroll
            for (int r = 0; r < 4; ++r)
                dst[cb + (size_t)(q_v * 16 + quad * 4 + r) * 8 + jv] = f2bf(acc[nt][r] + bias[r]);
        }
    }
}

// ---------------- 5. Flash: 1 wave/block, 32 Q rows, barrier-free, KV from L2 ----------------
// 1-D grid of 2048 64-thread blocks. lin&15 = (b,sp) chunk -> XCD-local KV.
__global__ void __launch_bounds__(64, 2) flash(const u16* __restrict__ qtf,
                                               const u16* __restrict__ ktf,
                                               const u16* __restrict__ vvf,
                                               u16* __restrict__ po,
                                               float* __restrict__ lp) {
    __shared__ u16 pbuf[32 * 36];          // block-private P tile (1 wave)
    int lin = blockIdx.x;
    int chunk = lin & 15;
    int nw = lin >> 4;                     // 0..127: wave index within chunk
    int b = chunk >> 2, sp = chunk & 3;
    int lane = threadIdx.x & 63;
    int l15 = lane & 15, quad = lane >> 4;
    const u16* qb = qtf + (size_t)b * NN * CC;
    const u16* kb = ktf + (size_t)b * NN * CC;
    const u16* vb = vvf + (size_t)b * NN * CC;

    // ones B-fragment (bf16 1.0 x8) for MFMA row-sum of P
    const u32x4 ones32 = {0x3F803F80u, 0x3F803F80u, 0x3F803F80u, 0x3F803F80u};
    const b16x8 vone = __builtin_bit_cast(b16x8, ones32);

    // Q: 32 rows per wave (2 a-tiles), held in registers
    b16x8 aq[2][8];
    #pragma unroll
    for (int a = 0; a < 2; ++a)
        #pragma unroll
        for (int kk = 0; kk < 8; ++kk)
            aq[a][kk] = ldfrag(qb + (size_t)((nw * 2 + a) * 8 + kk) * 512 + lane * 8);

    f32x4 acco[2][16] = {};
    f32x4 acco_l[2] = {};

    const int m_beg = sp * (NN / SPLITS);
    for (int it = 0; it < ITERS; ++it) {
        int m0 = m_beg + it * TKV;
        int mt0 = m0 >> 4, kv32 = m0 >> 5;
        // QK: accumulators init to -FMAX (folds softmax max subtraction)
        f32x4 accs[2][2];
        #pragma unroll
        for (int a = 0; a < 2; ++a)
            #pragma unroll
            for (int m = 0; m < 2; ++m) {
                accs[a][m][0] = -FMAX; accs[a][m][1] = -FMAX;
                accs[a][m][2] = -FMAX; accs[a][m][3] = -FMAX;
            }
        #pragma unroll
        for (int kk = 0; kk < 8; ++kk) {
            #pragma unroll
            for (int m = 0; m < 2; ++m) {
                b16x8 bk = ldfrag(kb + (size_t)((mt0 + m) * 8 + kk) * 512 + lane * 8);
                accs[0][m] = __builtin_amdgcn_mfma_f32_16x16x32_bf16(aq[0][kk], bk, accs[0][m], 0, 0, 0);
                accs[1][m] = __builtin_amdgcn_mfma_f32_16x16x32_bf16(aq[1][kk], bk, accs[1][m], 0, 0, 0);
            }
        }
        // P = exp2(S), pack pairwise (m=0,m=1) -> private LDS in A-frag layout
        #pragma unroll
        for (int a = 0; a < 2; ++a) {
            #pragma unroll
            for (int r = 0; r < 4; ++r) {
                float e0 = exp2_raw(accs[a][0][r]);
                float e1 = exp2_raw(accs[a][1][r]);
                u32 pk = pack_bf2(e0, e1);
                int row = a * 16 + quad * 4 + r;
                pbuf[row * 36 + l15]      = (u16)pk;
                pbuf[row * 36 + 16 + l15] = (u16)(pk >> 16);
            }
        }
        asm volatile("s_waitcnt lgkmcnt(0)" ::: "memory");   // same-wave LDS RAW
        b16x8 ap[2];
        #pragma unroll
        for (int a = 0; a < 2; ++a) {
            ap[a] = ldfrag(pbuf + (size_t)(a * 16 + l15) * 36 + quad * 8);
            acco_l[a] = __builtin_amdgcn_mfma_f32_16x16x32_bf16(ap[a], vone, acco_l[a], 0, 0, 0);
        }
        #pragma unroll
        for (int ct = 0; ct < 16; ++ct) {
            b16x8 bv = ldfrag(vb + (size_t)(ct * (NN / 32) + kv32) * 512 + lane * 8);
            acco[0][ct] = __builtin_amdgcn_mfma_f32_16x16x32_bf16(ap[0], bv, acco[0][ct], 0, 0, 0);
            acco[1][ct] = __builtin_amdgcn_mfma_f32_16x16x32_bf16(ap[1], bv, acco[1][ct], 0, 0, 0);
        }
    }
    // epilogue: po in raw C/D-lane chunk layout, u16x4 packed over r
    #pragma unroll
    for (int a = 0; a < 2; ++a) {
        int nchunk = nw * 2 + a;
        u16* pochunk = po + ((size_t)(sp * BB + b) * 256 + nchunk) * 4096;
        #pragma unroll
        for (int ct = 0; ct < 16; ++ct) {
            u32x2 st;
            st.x = pack_bf2(acco[a][ct][0], acco[a][ct][1]);
            st.y = pack_bf2(acco[a][ct][2], acco[a][ct][3]);
            *reinterpret_cast<u32x2*>(pochunk + (size_t)(ct * 64 + quad * 16 + l15) * 4) = st;
        }
        if (l15 == 0) {
            size_t lbase = (size_t)(sp * BB + b) * NN + nw * 32 + a * 16;
            #pragma unroll
            for (int r = 0; r < 4; ++r) lp[lbase + quad * 4 + r] = acco_l[a][r];
        }
    }
}

// ---- 5b. combine: sum po chunks / sum l -> otf (frag-major), all coalesced ----
__global__ void __launch_bounds__(256) combine(const u16* __restrict__ po,
                                               const float* __restrict__ lp,
                                               u16* __restrict__ otf) {
    int idx = blockIdx.x * 256 + threadIdx.x;   // 131072 threads
    int cg   = idx & 31;          // col group of 8 (c8 = cg*8)
    int quad = (idx >> 5) & 3;    // row quad within 16-row chunk
    int nb   = (idx >> 7) & 255;  // n chunk
    int b    = idx >> 15;
    float acc[4][8] = {};
    float lsum[4] = {};
    #pragma unroll
    for (int s = 0; s < SPLITS; ++s) {
        const u16* src = po + (((size_t)(s * BB + b) * 256 + nb) * 4096)
                       + ((cg >> 1) * 256 + quad * 64 + (cg & 1) * 32);
        u16 s16[32];
        #pragma unroll
        for (int q = 0; q < 4; ++q)
            *reinterpret_cast<u32x4*>(&s16[q * 8]) = *reinterpret_cast<const u32x4*>(src + q * 8);
        #pragma unroll
        for (int r = 0; r < 4; ++r)
            #pragma unroll
            for (int j = 0; j < 8; ++j)
                acc[r][j] += bf2f(s16[j * 4 + r]);
        #pragma unroll
        for (int r = 0; r < 4; ++r)
            lsum[r] += lp[(size_t)(s * BB + b) * NN + nb * 16 + quad * 4 + r];
    }
    u16* dstb = otf + (size_t)b * NN * CC;
    #pragma unroll
    for (int r = 0; r < 4; ++r) {
        float inv = 1.f / lsum[r];
        u16 outv[8];
        #pragma unroll
        for (int j = 0; j < 8; ++j) outv[j] = f2bf(acc[r][j] * inv);
        size_t off = ((size_t)(nb * 8 + (cg >> 2)) * 64 + (cg & 3) * 16 + quad * 4 + r) * 8;
        *reinterpret_cast<u32x4*>(dstb + off) = *reinterpret_cast<const u32x4*>(outv);
    }
}

// ------- 6. proj GEMM + bias + residual ----------------
__global__ void __launch_bounds__(256) proj(const u16* __restrict__ wpf,
                                            const float* __restrict__ b_proj,
                                            const u16* __restrict__ otf,
                                            const float* __restrict__ x,
                                            float* __restrict__ out) {
    int b = blockIdx.z, o0 = blockIdx.y * 64, n0 = blockIdx.x * 64;
    int lane = threadIdx.x & 63, w = threadIdx.x >> 6;
    int l15 = lane & 15, quad = lane >> 4;
    const u16* Bp = otf + (size_t)b * NN * CC;
    int otile = (o0 >> 4) + w;
    f32x4 acc[4] = {};
    #pragma unroll
    for (int kk = 0; kk < 8; ++kk) {
        b16x8 af = ldfrag(wpf + (size_t)(otile * 8 + kk) * 512 + lane * 8);
        #pragma unroll
        for (int nt = 0; nt < 4; ++nt) {
            b16x8 bf = ldfrag(Bp + (size_t)(((n0 >> 4) + nt) * 8 + kk) * 512 + lane * 8);
            acc[nt] = __builtin_amdgcn_mfma_f32_16x16x32_bf16(af, bf, acc[nt], 0, 0, 0);
        }
    }
    int o_base = o0 + w * 16 + quad * 4;
    #pragma unroll
    for (int nt = 0; nt < 4; ++nt) {
        int n = n0 + nt * 16 + l15;
        #pragma unroll
        for (int r = 0; r < 4; ++r) {
            int o = o_base + r;
            size_t idx = ((size_t)(b * CC + o)) * NN + n;
            out[idx] = acc[nt][r] + b_proj[o] + x[idx];
        }
    }
}

extern "C" void kernel_launch(void* const* d_in, const int* in_sizes, int n_in,
                              void* d_out, int out_size, void* d_ws, size_t ws_size,
                              hipStream_t stream) {
    const float* x      = (const float*)d_in[0];
    const float* gamma  = (const float*)d_in[1];
    const float* beta   = (const float*)d_in[2];
    const float* w_qkv  = (const float*)d_in[3];
    const float* w_proj = (const float*)d_in[4];
    const float* b_proj = (const float*)d_in[5];
    float* out = (float*)d_out;

    char* p = (char*)d_ws;
    float* stats = (float*)p; p += 256;
    float* gsum  = (float*)p; p += 256;
    float* biasq = (float*)p; p += (size_t)BB * 768 * sizeof(float);
    u16* wqf = (u16*)p; p += (size_t)BB * 768 * CC * 2;
    u16* wpf = (u16*)p; p += (size_t)CC * CC * 2;
    u16* xtf = (u16*)p; p += (size_t)BB * NN * CC * 2;
    u16* qtf = (u16*)p; p += (size_t)BB * NN * CC * 2;
    u16* ktf = (u16*)p; p += (size_t)BB * NN * CC * 2;
    u16* vvf = (u16*)p; p += (size_t)BB * NN * CC * 2;
    u16* otf = (u16*)p; p += (size_t)BB * NN * CC * 2;
    u16* po = (u16*)p; p += (size_t)SPLITS * BB * NN * CC * 2;
    float* lp = (float*)p; p += (size_t)SPLITS * BB * NN * sizeof(float);
    (void)ws_size; (void)in_sizes; (void)n_in; (void)out_size;

    (void)hipMemsetAsync(gsum, 0, BB * GG * 2 * sizeof(float), stream);
    transpose_x<<<dim3(NN / 64, CC / 64, BB), 256, 0, stream>>>(x, xtf, gsum);
    gn_finalize<<<1, 64, 0, stream>>>(gsum, stats);
    fold_w<<<dim3(768, BB), 256, 0, stream>>>(w_qkv, w_proj, gamma, beta, stats, wqf, biasq, wpf);
    qkv_gemm<<<dim3(NN / 64, 12, BB), 256, 0, stream>>>(wqf, biasq, xtf, qtf, ktf, vvf);
    flash<<<(NN / 32) * SPLITS * BB / 16 * 16, 64, 0, stream>>>(qtf, ktf, vvf, po, lp);
    combine<<<(BB * NN * CC / 32) / 256, 256, 0, stream>>>(po, lp, otf);
    proj<<<dim3(NN / 64, CC / 64, BB), 256, 0, stream>>>(wpf, b_proj, otf, x, out);
}

// Round 9
// 195.122 us; speedup vs baseline: 1.4443x; 1.4443x over previous
//
#include <hip/hip_runtime.h>
#include <hip/hip_bf16.h>

#define BB 4
#define CC 256
#define NN 4096
#define GG 8
#define SPLITS 4
#define MBLK 64
#define TKV 32
#define ITERS (NN / SPLITS / TKV)

typedef unsigned char u8;
typedef unsigned short u16;
typedef unsigned int u32;
typedef __bf16 b16x8 __attribute__((ext_vector_type(8)));
typedef float f32x4 __attribute__((ext_vector_type(4)));
typedef u32 u32x4 __attribute__((ext_vector_type(4)));
typedef u32 u32x2 __attribute__((ext_vector_type(2)));
typedef u16 u16x4 __attribute__((ext_vector_type(4)));

// softmax: P' = exp2(S_raw * QS - FMAX); QS = C^-0.5 * log2(e). FMAX=8 keeps
// P' inside e4m3's normal range (typ max ~2^-2, floor 2^-9). l,O scale-invariant.
#define QS 0.09016844005556021f
#define FMAX 8.0f

// bf16 fragment chunk (512 u16): elem(row,col32) = (quad(col32>>3)*16+row)*8+(col32&7)
// fp8 superchunk (1024 B, 16 rows x 64 cols): two 8B frags per lane:
//   addr(row,col) = ((col&31)>>3)*256 + row*16 + ((col>>5)&1)*8 + (col&7)
// fp8 V superchunk (1024 B, 32 c x 32 kv):
//   addr(c,kv) = ((kv&31)>>3)*256 + (c&15)*16 + ((c>>4)&1)*8 + (kv&7)

__device__ __forceinline__ u16 f2bf(float f) {
    u32 u = __builtin_bit_cast(u32, f);
    u = (u + 0x7FFFu + ((u >> 16) & 1u)) >> 16;
    return (u16)u;
}

__device__ __forceinline__ float bf2f(u16 h) {
    return __builtin_bit_cast(float, (u32)h << 16);
}

__device__ __forceinline__ u32 pack_bf2(float a, float b) {
    float2 f; f.x = a; f.y = b;
    __hip_bfloat162 h = __float22bfloat162_rn(f);
    u32 r;
    __builtin_memcpy(&r, &h, 4);
    return r;
}

__device__ __forceinline__ float exp2_raw(float x) {
#if __has_builtin(__builtin_amdgcn_exp2f)
    return __builtin_amdgcn_exp2f(x);
#else
    float r;
    asm("v_exp_f32 %0, %1" : "=v"(r) : "v"(x));
    return r;
#endif
}

__device__ __forceinline__ b16x8 ldfrag(const u16* p) {
    u32x4 v = *reinterpret_cast<const u32x4*>(p);
    return __builtin_bit_cast(b16x8, v);
}

__device__ __forceinline__ int pk_fp8x4(float a, float b, float c, float d) {
    int r = __builtin_amdgcn_cvt_pk_fp8_f32(a, b, 0, false);
    r = __builtin_amdgcn_cvt_pk_fp8_f32(c, d, r, true);
    return r;
}

__device__ __forceinline__ long as_long(u32x2 v) { return __builtin_bit_cast(long, v); }

typedef __attribute__((address_space(1))) const unsigned int* gas_p;
typedef __attribute__((address_space(3))) unsigned int* las_p;

__device__ __forceinline__ void g2l(const u8* g, u8* l) {
    __builtin_amdgcn_global_load_lds((gas_p)g, (las_p)l, 16, 0, 0);
}

// ------- 2. Fold GN into QKV weights (frag-major bf16) + frag-major w_proj -------
__global__ void fold_w(const float* __restrict__ w_qkv, const float* __restrict__ w_proj,
                       const float* __restrict__ gamma, const float* __restrict__ beta,
                       const float* __restrict__ stats,
                       u16* __restrict__ wqf, float* __restrict__ biasq,
                       u16* __restrict__ wpf) {
    int o = blockIdx.x;        // 0..767
    int b = blockIdx.y;        // 0..3
    int c = threadIdx.x;       // 0..255
    int g = c >> 5;
    float mu   = stats[(b * GG + g) * 2];
    float rstd = stats[(b * GG + g) * 2 + 1];
    float a  = gamma[c] * rstd;
    float bb = beta[c] - mu * a;
    float w = w_qkv[o * CC + c];
    size_t fe = ((size_t)((o >> 4) * 8 + (c >> 5)) * 64 + ((c & 31) >> 3) * 16 + (o & 15)) * 8 + (c & 7);
    wqf[(size_t)b * 768 * CC + fe] = f2bf(w * a);
    float part = w * bb;
    #pragma unroll
    for (int off = 32; off; off >>= 1) part += __shfl_down(part, off, 64);
    __shared__ float red[4];
    if ((threadIdx.x & 63) == 0) red[threadIdx.x >> 6] = part;
    __syncthreads();
    if (threadIdx.x == 0) biasq[b * 768 + o] = red[0] + red[1] + red[2] + red[3];
    if (b == 0 && o < CC) {
        float wp = w_proj[o * CC + c];
        wpf[fe] = f2bf(wp);
    }
}

// ---- 3. x [B][C][N] fp32 -> xt_frag bf16; fused GroupNorm partial sums ----
__global__ void transpose_x(const float* __restrict__ x, u16* __restrict__ xtf,
                            float* __restrict__ gsum) {
    __shared__ float tile[64][65];
    __shared__ float red[4][4];
    int n0 = blockIdx.x * 64, c0 = blockIdx.y * 64, b = blockIdx.z;
    int t = threadIdx.x;
    int col = t & 63, r0 = t >> 6;
    const float* xp = x + (size_t)b * CC * NN;
    float s0 = 0.f, ss0 = 0.f, s1 = 0.f, ss1 = 0.f;
    #pragma unroll
    for (int i = 0; i < 16; ++i) {
        int row = i * 4 + r0;
        float v = xp[(size_t)(c0 + row) * NN + n0 + col];
        tile[row][col] = v;
        if (i < 8) { s0 += v; ss0 += v * v; } else { s1 += v; ss1 += v * v; }
    }
    #pragma unroll
    for (int off = 32; off; off >>= 1) {
        s0 += __shfl_down(s0, off, 64); ss0 += __shfl_down(ss0, off, 64);
        s1 += __shfl_down(s1, off, 64); ss1 += __shfl_down(ss1, off, 64);
    }
    int wid = t >> 6;
    if ((t & 63) == 0) { red[wid][0] = s0; red[wid][1] = ss0; red[wid][2] = s1; red[wid][3] = ss1; }
    __syncthreads();
    if (t < 2) {
        float s  = red[0][t * 2] + red[1][t * 2] + red[2][t * 2] + red[3][t * 2];
        float ss = red[0][t * 2 + 1] + red[1][t * 2 + 1] + red[2][t * 2 + 1] + red[3][t * 2 + 1];
        int g = (c0 >> 5) + t;
        atomicAdd(&gsum[(b * GG + g) * 2], s);
        atomicAdd(&gsum[(b * GG + g) * 2 + 1], ss);
    }
    int nl = t >> 2;
    int cbq = t & 3;
    int l15 = nl & 15;
    int ntile = (n0 >> 4) + (nl >> 4);
    int kk = (c0 >> 5) + (cbq >> 1);
    u16* ob = xtf + (size_t)b * NN * CC;
    #pragma unroll
    for (int g = 0; g < 4; ++g) {
        int quad = (cbq & 1) * 2 + (g >> 1);
        int j0 = (g & 1) * 4;
        u16x4 v;
        v.x = f2bf(tile[cbq * 16 + g * 4 + 0][nl]);
        v.y = f2bf(tile[cbq * 16 + g * 4 + 1][nl]);
        v.z = f2bf(tile[cbq * 16 + g * 4 + 2][nl]);
        v.w = f2bf(tile[cbq * 16 + g * 4 + 3][nl]);
        *reinterpret_cast<u16x4*>(ob + ((size_t)(ntile * 8 + kk) * 64 + quad * 16 + l15) * 8 + j0) = v;
    }
}

// ---------------- 3b. finalize GN stats ----------------
__global__ void gn_finalize(const float* __restrict__ gsum, float* __restrict__ stats) {
    int i = threadIdx.x;
    if (i < BB * GG) {
        float s = gsum[i * 2], ss = gsum[i * 2 + 1];
        const float inv = 1.f / ((CC / GG) * NN);
        float mu = s * inv;
        float var = ss * inv - mu * mu;
        stats[i * 2] = mu;
        stats[i * 2 + 1] = rsqrtf(var + 1e-5f);
    }
}

// ------- 4. QKV GEMM (bf16 MFMA, fp32 acc) -> fp8 q/k superchunks, fp8 V superchunks -------
__global__ void __launch_bounds__(256) qkv_gemm(const u16* __restrict__ wqf,
                                                const float* __restrict__ biasq,
                                                const u16* __restrict__ xtf,
                                                u8* __restrict__ qtf, u8* __restrict__ ktf,
                                                u8* __restrict__ vvf) {
    int b = blockIdx.z;
    int o0 = blockIdx.y * 64;
    int n0 = blockIdx.x * 64;
    int lane = threadIdx.x & 63, w = threadIdx.x >> 6;
    int l15 = lane & 15, quad = lane >> 4;
    const u16* A  = wqf + (size_t)b * 768 * CC;
    const u16* Bp = xtf + (size_t)b * NN * CC;
    int otile = (o0 >> 4) + w;
    f32x4 acc[4] = {};
    #pragma unroll
    for (int kk = 0; kk < 8; ++kk) {
        b16x8 af = ldfrag(A + (size_t)(otile * 8 + kk) * 512 + lane * 8);
        #pragma unroll
        for (int nt = 0; nt < 4; ++nt) {
            b16x8 bf = ldfrag(Bp + (size_t)(((n0 >> 4) + nt) * 8 + kk) * 512 + lane * 8);
            acc[nt] = __builtin_amdgcn_mfma_f32_16x16x32_bf16(af, bf, acc[nt], 0, 0, 0);
        }
    }
    int o_base = o0 + w * 16 + quad * 4;
    float bias[4];
    #pragma unroll
    for (int r = 0; r < 4; ++r) bias[r] = biasq[b * 768 + o_base + r];

    if (o0 < 512) {
        // Q or K: fp8 superchunk [16 n][64 c]; no QSCALE (applied in flash)
        int oloc = (o0 < 256) ? o_base : (o_base - 256);   // c of r=0; (oloc&7) in {0,4}
        u8* dst = ((o0 < 256) ? qtf : ktf) + (size_t)b * NN * CC;
        #pragma unroll
        for (int nt = 0; nt < 4; ++nt) {
            int n = n0 + nt * 16 + l15;
            int pk = pk_fp8x4(acc[nt][0] + bias[0], acc[nt][1] + bias[1],
                              acc[nt][2] + bias[2], acc[nt][3] + bias[3]);
            size_t addr = (size_t)((n >> 4) * 4 + (oloc >> 6)) * 1024
                        + ((oloc & 31) >> 3) * 256 + (n & 15) * 16
                        + ((oloc >> 5) & 1) * 8 + (oloc & 7);
            *reinterpret_cast<u32*>(dst + addr) = (u32)pk;
        }
    } else {
        // V: fp8 superchunk [32 c][32 kv], schunk = (kv>>5)*8 + (c>>5)
        int cb = o_base - 512;
        u8* dst = vvf + (size_t)b * NN * CC;
        #pragma unroll
        for (int nt = 0; nt < 4; ++nt) {
            int kv = n0 + nt * 16 + l15;
            int pk = pk_fp8x4(acc[nt][0] + bias[0], acc[nt][1] + bias[1],
                              acc[nt][2] + bias[2], acc[nt][3] + bias[3]);
            size_t base = (size_t)((kv >> 5) * 8 + (cb >> 5)) * 1024
                        + ((kv & 31) >> 3) * 256 + ((cb >> 4) & 1) * 8 + (kv & 7);
            #pragma unroll
            for (int r = 0; r < 4; ++r)
                dst[base + ((cb & 15) + r) * 16] = (u8)(pk >> (r * 8));
        }
    }
}

// ---------------- 5. Flash: all-fp8, 16 q-rows/wave, 4 waves/SIMD target ----------------
// grid 1024 (= 4 blocks/CU exact); lin&15 = (b,sp) chunk -> XCD-local KV (L2-resident).
__global__ void __launch_bounds__(256, 4) flash(const u8* __restrict__ qtf,
                                                const u8* __restrict__ ktf,
                                                const u8* __restrict__ vvf,
                                                u16* __restrict__ po,
                                                float* __restrict__ lp) {
    __shared__ u8 kbuf[2][8192];
    __shared__ u8 vbuf[2][8192];
    __shared__ u8 pbuf[4][16 * 40];
    int lin = blockIdx.x;
    int chunk = lin & 15;
    int nblk = lin >> 4;                  // 0..63
    int b = chunk >> 2, sp = chunk & 3;
    int lane = threadIdx.x & 63, w = threadIdx.x >> 6;
    int l15 = lane & 15, quad = lane >> 4;
    int ntile = nblk * 4 + w;             // this wave's 16 q rows
    const u8* kb8 = ktf + (size_t)b * NN * CC;
    const u8* vb8 = vvf + (size_t)b * NN * CC;
    u8* pw = &pbuf[w][0];

    const u32x2 ones2 = {0x38383838u, 0x38383838u};   // e4m3 1.0 x8
    const long ones8 = as_long(ones2);

    // Q: 16 rows, 4 superchunks = 4 KB contiguous; b128 loads, reg-resident
    u32x4 aq[4];
    const u8* qb = qtf + (size_t)b * NN * CC + (size_t)ntile * 4096;
    #pragma unroll
    for (int s = 0; s < 4; ++s)
        aq[s] = *reinterpret_cast<const u32x4*>(qb + s * 1024 + lane * 16);

    f32x4 acco[16] = {};
    f32x4 acco_l = {};

    const int m_beg = sp * (NN / SPLITS);

    // stage one 32-kv tile: K 8KB + V 8KB, both contiguous at byte offset m0*256
    auto stage = [&](int buf, int m0) {
        const u8* ks = kb8 + ((size_t)m0 << 8);
        const u8* vs = vb8 + ((size_t)m0 << 8);
        #pragma unroll
        for (int j = 0; j < 4; ++j) {
            int idx = w * 4 + j;          // 0..15
            if (idx < 8) g2l(ks + idx * 1024 + lane * 16, &kbuf[buf][idx * 1024]);
            else         g2l(vs + (idx - 8) * 1024 + lane * 16, &vbuf[buf][(idx - 8) * 1024]);
        }
    };

    stage(0, m_beg);
    __syncthreads();
    for (int it = 0; it < ITERS; ++it) {
        int cur = it & 1;
        if (it + 1 < ITERS) stage(cur ^ 1, m_beg + (it + 1) * TKV);
        const u8* kc = &kbuf[cur][0];
        const u8* vc = &vbuf[cur][0];
        // S = Q K^T (raw, fp8): accs[m] over kv-tiles; K superchunks [mt][c64]
        f32x4 accs[2] = {};
        #pragma unroll
        for (int s = 0; s < 4; ++s) {     // c64 index
            long alo = as_long(u32x2{aq[s].x, aq[s].y});
            long ahi = as_long(u32x2{aq[s].z, aq[s].w});
            #pragma unroll
            for (int m = 0; m < 2; ++m) {
                u32x4 kf = *reinterpret_cast<const u32x4*>(kc + (size_t)(m * 4 + s) * 1024 + lane * 16);
                accs[m] = __builtin_amdgcn_mfma_f32_16x16x32_fp8_fp8(
                    alo, as_long(u32x2{kf.x, kf.y}), accs[m], 0, 0, 0);
                accs[m] = __builtin_amdgcn_mfma_f32_16x16x32_fp8_fp8(
                    ahi, as_long(u32x2{kf.z, kf.w}), accs[m], 0, 0, 0);
            }
        }
        // P' = exp2(S*QS - FMAX) -> fp8 bytes -> pbuf rows=q(16,stride 40), cols=kv(32)
        #pragma unroll
        for (int m = 0; m < 2; ++m) {
            float e0 = exp2_raw(fmaf(accs[m][0], QS, -FMAX));
            float e1 = exp2_raw(fmaf(accs[m][1], QS, -FMAX));
            float e2 = exp2_raw(fmaf(accs[m][2], QS, -FMAX));
            float e3 = exp2_raw(fmaf(accs[m][3], QS, -FMAX));
            int p01 = __builtin_amdgcn_cvt_pk_fp8_f32(e0, e1, 0, false);
            int p23 = __builtin_amdgcn_cvt_pk_fp8_f32(e2, e3, 0, false);
            u8* pr = pw + m * 16 + l15;
            pr[(quad * 4 + 0) * 40] = (u8)p01;
            pr[(quad * 4 + 1) * 40] = (u8)(p01 >> 8);
            pr[(quad * 4 + 2) * 40] = (u8)p23;
            pr[(quad * 4 + 3) * 40] = (u8)(p23 >> 8);
        }
        asm volatile("s_waitcnt lgkmcnt(0)" ::: "memory");
        u32x2 apv = *reinterpret_cast<const u32x2*>(pw + l15 * 40 + quad * 8);
        long ap = as_long(apv);
        acco_l = __builtin_amdgcn_mfma_f32_16x16x32_fp8_fp8(ap, ones8, acco_l, 0, 0, 0);
        // O += P' V : V superchunks [ct-pair], b128 each
        #pragma unroll
        for (int c2 = 0; c2 < 8; ++c2) {
            u32x4 vf = *reinterpret_cast<const u32x4*>(vc + (size_t)c2 * 1024 + lane * 16);
            acco[c2 * 2]     = __builtin_amdgcn_mfma_f32_16x16x32_fp8_fp8(
                ap, as_long(u32x2{vf.x, vf.y}), acco[c2 * 2], 0, 0, 0);
            acco[c2 * 2 + 1] = __builtin_amdgcn_mfma_f32_16x16x32_fp8_fp8(
                ap, as_long(u32x2{vf.z, vf.w}), acco[c2 * 2 + 1], 0, 0, 0);
        }
        __syncthreads();
    }
    // epilogue: po chunk (16 q x 256 c) in C/D-lane layout (same format as before)
    u16* pochunk = po + ((size_t)(sp * BB + b) * 256 + ntile) * 4096;
    #pragma unroll
    for (int ct = 0; ct < 16; ++ct) {
        u32x2 st;
        st.x = pack_bf2(acco[ct][0], acco[ct][1]);
        st.y = pack_bf2(acco[ct][2], acco[ct][3]);
        *reinterpret_cast<u32x2*>(pochunk + (size_t)(ct * 64 + quad * 16 + l15) * 4) = st;
    }
    if (l15 == 0) {
        size_t lbase = (size_t)(sp * BB + b) * NN + ntile * 16;
        #pragma unroll
        for (int r = 0; r < 4; ++r) lp[lbase + quad * 4 + r] = acco_l[r];
    }
}

// ---- 5b. combine: sum po chunks / sum l -> otf (frag-major bf16), coalesced ----
__global__ void __launch_bounds__(256) combine(const u16* __restrict__ po,
                                               const float* __restrict__ lp,
                                               u16* __restrict__ otf) {
    int idx = blockIdx.x * 256 + threadIdx.x;   // 131072 threads
    int cg   = idx & 31;          // col group of 8 (c8 = cg*8)
    int quad = (idx >> 5) & 3;    // row quad within 16-row chunk
    int nb   = (idx >> 7) & 255;  // n chunk
    int b    = idx >> 15;
    float acc[4][8] = {};
    float lsum[4] = {};
    #pragma unroll
    for (int s = 0; s < SPLITS; ++s) {
        const u16* src = po + (((size_t)(s * BB + b) * 256 + nb) * 4096)
                       + ((cg >> 1) * 256 + quad * 64 + (cg & 1) * 32);
        u16 s16[32];
        #pragma unroll
        for (int q = 0; q < 4; ++q)
            *reinterpret_cast<u32x4*>(&s16[q * 8]) = *reinterpret_cast<const u32x4*>(src + q * 8);
        #pragma unroll
        for (int r = 0; r < 4; ++r)
            #pragma unroll
            for (int j = 0; j < 8; ++j)
                acc[r][j] += bf2f(s16[j * 4 + r]);
        #pragma unroll
        for (int r = 0; r < 4; ++r)
            lsum[r] += lp[(size_t)(s * BB + b) * NN + nb * 16 + quad * 4 + r];
    }
    u16* dstb = otf + (size_t)b * NN * CC;
    #pragma unroll
    for (int r = 0; r < 4; ++r) {
        float inv = 1.f / lsum[r];
        u16 outv[8];
        #pragma unroll
        for (int j = 0; j < 8; ++j) outv[j] = f2bf(acc[r][j] * inv);
        size_t off = ((size_t)(nb * 8 + (cg >> 2)) * 64 + (cg & 3) * 16 + quad * 4 + r) * 8;
        *reinterpret_cast<u32x4*>(dstb + off) = *reinterpret_cast<const u32x4*>(outv);
    }
}

// ------- 6. proj GEMM + bias + residual ----------------
__global__ void __launch_bounds__(256) proj(const u16* __restrict__ wpf,
                                            const float* __restrict__ b_proj,
                                            const u16* __restrict__ otf,
                                            const float* __restrict__ x,
                                            float* __restrict__ out) {
    int b = blockIdx.z, o0 = blockIdx.y * 64, n0 = blockIdx.x * 64;
    int lane = threadIdx.x & 63, w = threadIdx.x >> 6;
    int l15 = lane & 15, quad = lane >> 4;
    const u16* Bp = otf + (size_t)b * NN * CC;
    int otile = (o0 >> 4) + w;
    f32x4 acc[4] = {};
    #pragma unroll
    for (int kk = 0; kk < 8; ++kk) {
        b16x8 af = ldfrag(wpf + (size_t)(otile * 8 + kk) * 512 + lane * 8);
        #pragma unroll
        for (int nt = 0; nt < 4; ++nt) {
            b16x8 bf = ldfrag(Bp + (size_t)(((n0 >> 4) + nt) * 8 + kk) * 512 + lane * 8);
            acc[nt] = __builtin_amdgcn_mfma_f32_16x16x32_bf16(af, bf, acc[nt], 0, 0, 0);
        }
    }
    int o_base = o0 + w * 16 + quad * 4;
    #pragma unroll
    for (int nt = 0; nt < 4; ++nt) {
        int n = n0 + nt * 16 + l15;
        #pragma unroll
        for (int r = 0; r < 4; ++r) {
            int o = o_base + r;
            size_t idx = ((size_t)(b * CC + o)) * NN + n;
            out[idx] = acc[nt][r] + b_proj[o] + x[idx];
        }
    }
}

extern "C" void kernel_launch(void* const* d_in, const int* in_sizes, int n_in,
                              void* d_out, int out_size, void* d_ws, size_t ws_size,
                              hipStream_t stream) {
    const float* x      = (const float*)d_in[0];
    const float* gamma  = (const float*)d_in[1];
    const float* beta   = (const float*)d_in[2];
    const float* w_qkv  = (const float*)d_in[3];
    const float* w_proj = (const float*)d_in[4];
    const float* b_proj = (const float*)d_in[5];
    float* out = (float*)d_out;

    char* p = (char*)d_ws;
    float* stats = (float*)p; p += 256;
    float* gsum  = (float*)p; p += 256;
    float* biasq = (float*)p; p += (size_t)BB * 768 * sizeof(float);
    u16* wqf = (u16*)p; p += (size_t)BB * 768 * CC * 2;
    u16* wpf = (u16*)p; p += (size_t)CC * CC * 2;
    u16* xtf = (u16*)p; p += (size_t)BB * NN * CC * 2;
    u8* qtf8 = (u8*)p; p += (size_t)BB * NN * CC;
    u8* ktf8 = (u8*)p; p += (size_t)BB * NN * CC;
    u8* vvf8 = (u8*)p; p += (size_t)BB * NN * CC;
    u16* otf = (u16*)p; p += (size_t)BB * NN * CC * 2;
    u16* po = (u16*)p; p += (size_t)SPLITS * BB * NN * CC * 2;
    float* lp = (float*)p; p += (size_t)SPLITS * BB * NN * sizeof(float);
    (void)ws_size; (void)in_sizes; (void)n_in; (void)out_size;

    (void)hipMemsetAsync(gsum, 0, BB * GG * 2 * sizeof(float), stream);
    transpose_x<<<dim3(NN / 64, CC / 64, BB), 256, 0, stream>>>(x, xtf, gsum);
    gn_finalize<<<1, 64, 0, stream>>>(gsum, stats);
    fold_w<<<dim3(768, BB), 256, 0, stream>>>(w_qkv, w_proj, gamma, beta, stats, wqf, biasq, wpf);
    qkv_gemm<<<dim3(NN / 64, 12, BB), 256, 0, stream>>>(wqf, biasq, xtf, qtf8, ktf8, vvf8);
    flash<<<(NN / MBLK) * SPLITS * BB, 256, 0, stream>>>(qtf8, ktf8, vvf8, po, lp);
    combine<<<(BB * NN * CC / 32) / 256, 256, 0, stream>>>(po, lp, otf);
    proj<<<dim3(NN / 64, CC / 64, BB), 256, 0, stream>>>(wpf, b_proj, otf, x, out);
}

// Round 10
// 185.016 us; speedup vs baseline: 1.5232x; 1.0546x over previous
//
#include <hip/hip_runtime.h>
#include <hip/hip_bf16.h>

#define BB 4
#define CC 256
#define NN 4096
#define GG 8
#define SPLITS 4
#define TKV 64
#define ITERS (NN / SPLITS / TKV)

typedef unsigned char u8;
typedef unsigned short u16;
typedef unsigned int u32;
typedef __bf16 b16x8 __attribute__((ext_vector_type(8)));
typedef float f32x4 __attribute__((ext_vector_type(4)));
typedef u32 u32x4 __attribute__((ext_vector_type(4)));
typedef u32 u32x2 __attribute__((ext_vector_type(2)));
typedef u16 u16x4 __attribute__((ext_vector_type(4)));

// softmax: P' = exp2(S_raw * QS - FMAX); QS = C^-0.5 * log2(e). FMAX=8 keeps
// P' inside e4m3's normal range. l,O scale-invariant.
#define QS 0.09016844005556021f
#define FMAX 8.0f

// bf16 fragment chunk (512 u16): elem(row,col32) = (quad(col32>>3)*16+row)*8+(col32&7)
// fp8 superchunk (1024 B, 16 rows x 64 cols): two 8B frags per lane:
//   addr(row,col) = ((col&31)>>3)*256 + row*16 + ((col>>5)&1)*8 + (col&7)
// fp8 V superchunk (1024 B, 32 c x 32 kv):
//   addr(c,kv) = ((kv&31)>>3)*256 + (c&15)*16 + ((c>>4)&1)*8 + (kv&7)

__device__ __forceinline__ u16 f2bf(float f) {
    u32 u = __builtin_bit_cast(u32, f);
    u = (u + 0x7FFFu + ((u >> 16) & 1u)) >> 16;
    return (u16)u;
}

__device__ __forceinline__ float bf2f(u16 h) {
    return __builtin_bit_cast(float, (u32)h << 16);
}

__device__ __forceinline__ u32 pack_bf2(float a, float b) {
    float2 f; f.x = a; f.y = b;
    __hip_bfloat162 h = __float22bfloat162_rn(f);
    u32 r;
    __builtin_memcpy(&r, &h, 4);
    return r;
}

__device__ __forceinline__ float exp2_raw(float x) {
#if __has_builtin(__builtin_amdgcn_exp2f)
    return __builtin_amdgcn_exp2f(x);
#else
    float r;
    asm("v_exp_f32 %0, %1" : "=v"(r) : "v"(x));
    return r;
#endif
}

__device__ __forceinline__ b16x8 ldfrag(const u16* p) {
    u32x4 v = *reinterpret_cast<const u32x4*>(p);
    return __builtin_bit_cast(b16x8, v);
}

__device__ __forceinline__ int pk_fp8x4(float a, float b, float c, float d) {
    int r = __builtin_amdgcn_cvt_pk_fp8_f32(a, b, 0, false);
    r = __builtin_amdgcn_cvt_pk_fp8_f32(c, d, r, true);
    return r;
}

__device__ __forceinline__ long as_long(u32x2 v) { return __builtin_bit_cast(long, v); }

typedef __attribute__((address_space(1))) const unsigned int* gas_p;
typedef __attribute__((address_space(3))) unsigned int* las_p;

__device__ __forceinline__ void g2l(const u8* g, u8* l) {
    __builtin_amdgcn_global_load_lds((gas_p)g, (las_p)l, 16, 0, 0);
}

__device__ __forceinline__ void g2l16(const u16* g, u16* l) {
    __builtin_amdgcn_global_load_lds((gas_p)g, (las_p)l, 16, 0, 0);
}

// ------- 2. Fold GN into QKV weights (frag-major bf16) + frag-major w_proj -------
__global__ void fold_w(const float* __restrict__ w_qkv, const float* __restrict__ w_proj,
                       const float* __restrict__ gamma, const float* __restrict__ beta,
                       const float* __restrict__ stats,
                       u16* __restrict__ wqf, float* __restrict__ biasq,
                       u16* __restrict__ wpf) {
    int o = blockIdx.x;        // 0..767
    int b = blockIdx.y;        // 0..3
    int c = threadIdx.x;       // 0..255
    int g = c >> 5;
    float mu   = stats[(b * GG + g) * 2];
    float rstd = stats[(b * GG + g) * 2 + 1];
    float a  = gamma[c] * rstd;
    float bb = beta[c] - mu * a;
    float w = w_qkv[o * CC + c];
    size_t fe = ((size_t)((o >> 4) * 8 + (c >> 5)) * 64 + ((c & 31) >> 3) * 16 + (o & 15)) * 8 + (c & 7);
    wqf[(size_t)b * 768 * CC + fe] = f2bf(w * a);
    float part = w * bb;
    #pragma unroll
    for (int off = 32; off; off >>= 1) part += __shfl_down(part, off, 64);
    __shared__ float red[4];
    if ((threadIdx.x & 63) == 0) red[threadIdx.x >> 6] = part;
    __syncthreads();
    if (threadIdx.x == 0) biasq[b * 768 + o] = red[0] + red[1] + red[2] + red[3];
    if (b == 0 && o < CC) {
        float wp = w_proj[o * CC + c];
        wpf[fe] = f2bf(wp);
    }
}

// ---- 3. x [B][C][N] fp32 -> xt_frag bf16; fused GroupNorm partial sums ----
__global__ void transpose_x(const float* __restrict__ x, u16* __restrict__ xtf,
                            float* __restrict__ gsum) {
    __shared__ float tile[64][65];
    __shared__ float red[4][4];
    int n0 = blockIdx.x * 64, c0 = blockIdx.y * 64, b = blockIdx.z;
    int t = threadIdx.x;
    int col = t & 63, r0 = t >> 6;
    const float* xp = x + (size_t)b * CC * NN;
    float s0 = 0.f, ss0 = 0.f, s1 = 0.f, ss1 = 0.f;
    #pragma unroll
    for (int i = 0; i < 16; ++i) {
        int row = i * 4 + r0;
        float v = xp[(size_t)(c0 + row) * NN + n0 + col];
        tile[row][col] = v;
        if (i < 8) { s0 += v; ss0 += v * v; } else { s1 += v; ss1 += v * v; }
    }
    #pragma unroll
    for (int off = 32; off; off >>= 1) {
        s0 += __shfl_down(s0, off, 64); ss0 += __shfl_down(ss0, off, 64);
        s1 += __shfl_down(s1, off, 64); ss1 += __shfl_down(ss1, off, 64);
    }
    int wid = t >> 6;
    if ((t & 63) == 0) { red[wid][0] = s0; red[wid][1] = ss0; red[wid][2] = s1; red[wid][3] = ss1; }
    __syncthreads();
    if (t < 2) {
        float s  = red[0][t * 2] + red[1][t * 2] + red[2][t * 2] + red[3][t * 2];
        float ss = red[0][t * 2 + 1] + red[1][t * 2 + 1] + red[2][t * 2 + 1] + red[3][t * 2 + 1];
        int g = (c0 >> 5) + t;
        atomicAdd(&gsum[(b * GG + g) * 2], s);
        atomicAdd(&gsum[(b * GG + g) * 2 + 1], ss);
    }
    int nl = t >> 2;
    int cbq = t & 3;
    int l15 = nl & 15;
    int ntile = (n0 >> 4) + (nl >> 4);
    int kk = (c0 >> 5) + (cbq >> 1);
    u16* ob = xtf + (size_t)b * NN * CC;
    #pragma unroll
    for (int g = 0; g < 4; ++g) {
        int quad = (cbq & 1) * 2 + (g >> 1);
        int j0 = (g & 1) * 4;
        u16x4 v;
        v.x = f2bf(tile[cbq * 16 + g * 4 + 0][nl]);
        v.y = f2bf(tile[cbq * 16 + g * 4 + 1][nl]);
        v.z = f2bf(tile[cbq * 16 + g * 4 + 2][nl]);
        v.w = f2bf(tile[cbq * 16 + g * 4 + 3][nl]);
        *reinterpret_cast<u16x4*>(ob + ((size_t)(ntile * 8 + kk) * 64 + quad * 16 + l15) * 8 + j0) = v;
    }
}

// ---------------- 3b. finalize GN stats ----------------
__global__ void gn_finalize(const float* __restrict__ gsum, float* __restrict__ stats) {
    int i = threadIdx.x;
    if (i < BB * GG) {
        float s = gsum[i * 2], ss = gsum[i * 2 + 1];
        const float inv = 1.f / ((CC / GG) * NN);
        float mu = s * inv;
        float var = ss * inv - mu * mu;
        stats[i * 2] = mu;
        stats[i * 2 + 1] = rsqrtf(var + 1e-5f);
    }
}

// ------- 4. QKV GEMM: LDS-staged B-tile, 128 o-rows/block -> fp8 q/k/v superchunks -------
__global__ void __launch_bounds__(256) qkv_gemm(const u16* __restrict__ wqf,
                                                const float* __restrict__ biasq,
                                                const u16* __restrict__ xtf,
                                                u8* __restrict__ qtf, u8* __restrict__ ktf,
                                                u8* __restrict__ vvf) {
    __shared__ u16 bx[16384];     // 64 n x 256 c bf16 frag tile, 32 KB contiguous
    int b = blockIdx.z;
    int o0 = blockIdx.y * 128;    // 0,128,...,640 — never spans Q/K/V boundary
    int n0 = blockIdx.x * 64;
    int lane = threadIdx.x & 63, w = threadIdx.x >> 6;
    int l15 = lane & 15, quad = lane >> 4;
    // stage B tile: chunks (n0/16*8 .. +32) are contiguous 32 KB
    const u16* Bg = xtf + (size_t)b * NN * CC + (size_t)n0 * 256;
    #pragma unroll
    for (int j = 0; j < 8; ++j) {
        int c = w * 8 + j;
        g2l16(Bg + (size_t)c * 512 + lane * 8, bx + (size_t)c * 512 + lane * 8);
    }
    __syncthreads();

    const u16* A = wqf + (size_t)b * 768 * CC;
    f32x4 acc[2][4] = {};
    #pragma unroll
    for (int kk = 0; kk < 8; ++kk) {
        b16x8 af[2];
        #pragma unroll
        for (int t = 0; t < 2; ++t) {
            int otile = (o0 >> 4) + w * 2 + t;
            af[t] = ldfrag(A + (size_t)(otile * 8 + kk) * 512 + lane * 8);
        }
        #pragma unroll
        for (int nt = 0; nt < 4; ++nt) {
            b16x8 bf = ldfrag(bx + (size_t)(nt * 8 + kk) * 512 + lane * 8);
            acc[0][nt] = __builtin_amdgcn_mfma_f32_16x16x32_bf16(af[0], bf, acc[0][nt], 0, 0, 0);
            acc[1][nt] = __builtin_amdgcn_mfma_f32_16x16x32_bf16(af[1], bf, acc[1][nt], 0, 0, 0);
        }
    }
    #pragma unroll
    for (int t = 0; t < 2; ++t) {
        int o_base = o0 + (w * 2 + t) * 16 + quad * 4;
        float bias[4];
        #pragma unroll
        for (int r = 0; r < 4; ++r) bias[r] = biasq[b * 768 + o_base + r];
        if (o0 < 512) {
            // Q or K: fp8 superchunk [16 n][64 c]
            int oloc = (o0 < 256) ? o_base : (o_base - 256);
            u8* dst = ((o0 < 256) ? qtf : ktf) + (size_t)b * NN * CC;
            #pragma unroll
            for (int nt = 0; nt < 4; ++nt) {
                int n = n0 + nt * 16 + l15;
                int pk = pk_fp8x4(acc[t][nt][0] + bias[0], acc[t][nt][1] + bias[1],
                                  acc[t][nt][2] + bias[2], acc[t][nt][3] + bias[3]);
                size_t addr = (size_t)((n >> 4) * 4 + (oloc >> 6)) * 1024
                            + ((oloc & 31) >> 3) * 256 + (n & 15) * 16
                            + ((oloc >> 5) & 1) * 8 + (oloc & 7);
                *reinterpret_cast<u32*>(dst + addr) = (u32)pk;
            }
        } else {
            // V: fp8 superchunk [32 c][32 kv]
            int cb = o_base - 512;
            u8* dst = vvf + (size_t)b * NN * CC;
            #pragma unroll
            for (int nt = 0; nt < 4; ++nt) {
                int kv = n0 + nt * 16 + l15;
                int pk = pk_fp8x4(acc[t][nt][0] + bias[0], acc[t][nt][1] + bias[1],
                                  acc[t][nt][2] + bias[2], acc[t][nt][3] + bias[3]);
                size_t base = (size_t)((kv >> 5) * 8 + (cb >> 5)) * 1024
                            + ((kv & 31) >> 3) * 256 + ((cb >> 4) & 1) * 8 + (kv & 7);
                #pragma unroll
                for (int r = 0; r < 4; ++r)
                    dst[base + ((cb & 15) + r) * 16] = (u8)(pk >> (r * 8));
            }
        }
    }
}

// ----- 5. Flash: all-fp8, 512-thread blocks, TKV=64, half the barriers of R9 -----
// grid 512 (= 2 blocks/CU, 4 waves/SIMD); lin&15 = (b,sp) chunk -> XCD-local KV.
__global__ void __launch_bounds__(512, 4) flash(const u8* __restrict__ qtf,
                                                const u8* __restrict__ ktf,
                                                const u8* __restrict__ vvf,
                                                u16* __restrict__ po,
                                                float* __restrict__ lp) {
    __shared__ u8 kbuf[2][16384];
    __shared__ u8 vbuf[2][16384];
    __shared__ u8 pbuf[8][16 * 72];
    int lin = blockIdx.x;
    int chunk = lin & 15;
    int nblk = lin >> 4;                  // 0..31
    int b = chunk >> 2, sp = chunk & 3;
    int lane = threadIdx.x & 63, w = threadIdx.x >> 6;   // w 0..7
    int l15 = lane & 15, quad = lane >> 4;
    int ntile = nblk * 8 + w;             // this wave's 16 q rows (0..255)
    const u8* kb8 = ktf + (size_t)b * NN * CC;
    const u8* vb8 = vvf + (size_t)b * NN * CC;
    u8* pw = &pbuf[w][0];

    const u32x2 ones2 = {0x38383838u, 0x38383838u};   // e4m3 1.0 x8
    const long ones8 = as_long(ones2);

    // Q: 16 rows, 4 superchunks = 4 KB contiguous; b128 loads, reg-resident
    u32x4 aq[4];
    const u8* qb = qtf + (size_t)b * NN * CC + (size_t)ntile * 4096;
    #pragma unroll
    for (int s = 0; s < 4; ++s)
        aq[s] = *reinterpret_cast<const u32x4*>(qb + s * 1024 + lane * 16);

    f32x4 acco[16] = {};
    f32x4 acco_l = {};

    const int m_beg = sp * (NN / SPLITS);

    // stage one 64-kv tile: K 16KB + V 16KB, both contiguous at byte offset m0*256
    auto stage = [&](int buf, int m0) {
        const u8* ks = kb8 + ((size_t)m0 << 8);
        const u8* vs = vb8 + ((size_t)m0 << 8);
        #pragma unroll
        for (int j = 0; j < 4; ++j) {
            int idx = w * 4 + j;          // 0..31
            if (idx < 16) g2l(ks + idx * 1024 + lane * 16, &kbuf[buf][idx * 1024]);
            else          g2l(vs + (idx - 16) * 1024 + lane * 16, &vbuf[buf][(idx - 16) * 1024]);
        }
    };

    stage(0, m_beg);
    __syncthreads();
    for (int it = 0; it < ITERS; ++it) {
        int cur = it & 1;
        if (it + 1 < ITERS) stage(cur ^ 1, m_beg + (it + 1) * TKV);
        const u8* kc = &kbuf[cur][0];
        const u8* vc = &vbuf[cur][0];
        // S = Q K^T (raw, fp8): 4 kv-tiles of 16; K superchunks [mt][c64]
        f32x4 accs[4] = {};
        #pragma unroll
        for (int s = 0; s < 4; ++s) {     // c64 index
            long alo = as_long(u32x2{aq[s].x, aq[s].y});
            long ahi = as_long(u32x2{aq[s].z, aq[s].w});
            #pragma unroll
            for (int m = 0; m < 4; ++m) {
                u32x4 kf = *reinterpret_cast<const u32x4*>(kc + (size_t)(m * 4 + s) * 1024 + lane * 16);
                accs[m] = __builtin_amdgcn_mfma_f32_16x16x32_fp8_fp8(
                    alo, as_long(u32x2{kf.x, kf.y}), accs[m], 0, 0, 0);
                accs[m] = __builtin_amdgcn_mfma_f32_16x16x32_fp8_fp8(
                    ahi, as_long(u32x2{kf.z, kf.w}), accs[m], 0, 0, 0);
            }
        }
        // P' = exp2(S*QS - FMAX) -> fp8 bytes -> pbuf rows=q(16, stride 72), cols=kv(64)
        #pragma unroll
        for (int m = 0; m < 4; ++m) {
            float e0 = exp2_raw(fmaf(accs[m][0], QS, -FMAX));
            float e1 = exp2_raw(fmaf(accs[m][1], QS, -FMAX));
            float e2 = exp2_raw(fmaf(accs[m][2], QS, -FMAX));
            float e3 = exp2_raw(fmaf(accs[m][3], QS, -FMAX));
            int p01 = __builtin_amdgcn_cvt_pk_fp8_f32(e0, e1, 0, false);
            int p23 = __builtin_amdgcn_cvt_pk_fp8_f32(e2, e3, 0, false);
            u8* pr = pw + m * 16 + l15;
            pr[(quad * 4 + 0) * 72] = (u8)p01;
            pr[(quad * 4 + 1) * 72] = (u8)(p01 >> 8);
            pr[(quad * 4 + 2) * 72] = (u8)p23;
            pr[(quad * 4 + 3) * 72] = (u8)(p23 >> 8);
        }
        asm volatile("s_waitcnt lgkmcnt(0)" ::: "memory");
        long ap0 = as_long(*reinterpret_cast<const u32x2*>(pw + l15 * 72 + quad * 8));
        long ap1 = as_long(*reinterpret_cast<const u32x2*>(pw + l15 * 72 + 32 + quad * 8));
        acco_l = __builtin_amdgcn_mfma_f32_16x16x32_fp8_fp8(ap0, ones8, acco_l, 0, 0, 0);
        acco_l = __builtin_amdgcn_mfma_f32_16x16x32_fp8_fp8(ap1, ones8, acco_l, 0, 0, 0);
        // O += P' V : kv 0..31 via ap0 x V chunks 0..7; kv 32..63 via ap1 x chunks 8..15
        #pragma unroll
        for (int c2 = 0; c2 < 8; ++c2) {
            u32x4 vf0 = *reinterpret_cast<const u32x4*>(vc + (size_t)c2 * 1024 + lane * 16);
            u32x4 vf1 = *reinterpret_cast<const u32x4*>(vc + (size_t)(8 + c2) * 1024 + lane * 16);
            acco[c2 * 2]     = __builtin_amdgcn_mfma_f32_16x16x32_fp8_fp8(
                ap0, as_long(u32x2{vf0.x, vf0.y}), acco[c2 * 2], 0, 0, 0);
            acco[c2 * 2 + 1] = __builtin_amdgcn_mfma_f32_16x16x32_fp8_fp8(
                ap0, as_long(u32x2{vf0.z, vf0.w}), acco[c2 * 2 + 1], 0, 0, 0);
            acco[c2 * 2]     = __builtin_amdgcn_mfma_f32_16x16x32_fp8_fp8(
                ap1, as_long(u32x2{vf1.x, vf1.y}), acco[c2 * 2], 0, 0, 0);
            acco[c2 * 2 + 1] = __builtin_amdgcn_mfma_f32_16x16x32_fp8_fp8(
                ap1, as_long(u32x2{vf1.z, vf1.w}), acco[c2 * 2 + 1], 0, 0, 0);
        }
        __syncthreads();
    }
    // epilogue: po chunk (16 q x 256 c) in C/D-lane layout
    u16* pochunk = po + ((size_t)(sp * BB + b) * 256 + ntile) * 4096;
    #pragma unroll
    for (int ct = 0; ct < 16; ++ct) {
        u32x2 st;
        st.x = pack_bf2(acco[ct][0], acco[ct][1]);
        st.y = pack_bf2(acco[ct][2], acco[ct][3]);
        *reinterpret_cast<u32x2*>(pochunk + (size_t)(ct * 64 + quad * 16 + l15) * 4) = st;
    }
    if (l15 == 0) {
        size_t lbase = (size_t)(sp * BB + b) * NN + ntile * 16;
        #pragma unroll
        for (int r = 0; r < 4; ++r) lp[lbase + quad * 4 + r] = acco_l[r];
    }
}

// ---- 5b. combine: sum po chunks / sum l -> otf (frag-major bf16), coalesced ----
__global__ void __launch_bounds__(256) combine(const u16* __restrict__ po,
                                               const float* __restrict__ lp,
                                               u16* __restrict__ otf) {
    int idx = blockIdx.x * 256 + threadIdx.x;   // 131072 threads
    int cg   = idx & 31;          // col group of 8 (c8 = cg*8)
    int quad = (idx >> 5) & 3;    // row quad within 16-row chunk
    int nb   = (idx >> 7) & 255;  // n chunk
    int b    = idx >> 15;
    float acc[4][8] = {};
    float lsum[4] = {};
    #pragma unroll
    for (int s = 0; s < SPLITS; ++s) {
        const u16* src = po + (((size_t)(s * BB + b) * 256 + nb) * 4096)
                       + ((cg >> 1) * 256 + quad * 64 + (cg & 1) * 32);
        u16 s16[32];
        #pragma unroll
        for (int q = 0; q < 4; ++q)
            *reinterpret_cast<u32x4*>(&s16[q * 8]) = *reinterpret_cast<const u32x4*>(src + q * 8);
        #pragma unroll
        for (int r = 0; r < 4; ++r)
            #pragma unroll
            for (int j = 0; j < 8; ++j)
                acc[r][j] += bf2f(s16[j * 4 + r]);
        #pragma unroll
        for (int r = 0; r < 4; ++r)
            lsum[r] += lp[(size_t)(s * BB + b) * NN + nb * 16 + quad * 4 + r];
    }
    u16* dstb = otf + (size_t)b * NN * CC;
    #pragma unroll
    for (int r = 0; r < 4; ++r) {
        float inv = 1.f / lsum[r];
        u16 outv[8];
        #pragma unroll
        for (int j = 0; j < 8; ++j) outv[j] = f2bf(acc[r][j] * inv);
        size_t off = ((size_t)(nb * 8 + (cg >> 2)) * 64 + (cg & 3) * 16 + quad * 4 + r) * 8;
        *reinterpret_cast<u32x4*>(dstb + off) = *reinterpret_cast<const u32x4*>(outv);
    }
}

// ------- 6. proj GEMM + bias + residual ----------------
__global__ void __launch_bounds__(256) proj(const u16* __restrict__ wpf,
                                            const float* __restrict__ b_proj,
                                            const u16* __restrict__ otf,
                                            const float* __restrict__ x,
                                            float* __restrict__ out) {
    int b = blockIdx.z, o0 = blockIdx.y * 64, n0 = blockIdx.x * 64;
    int lane = threadIdx.x & 63, w = threadIdx.x >> 6;
    int l15 = lane & 15, quad = lane >> 4;
    const u16* Bp = otf + (size_t)b * NN * CC;
    int otile = (o0 >> 4) + w;
    f32x4 acc[4] = {};
    #pragma unroll
    for (int kk = 0; kk < 8; ++kk) {
        b16x8 af = ldfrag(wpf + (size_t)(otile * 8 + kk) * 512 + lane * 8);
        #pragma unroll
        for (int nt = 0; nt < 4; ++nt) {
            b16x8 bf = ldfrag(Bp + (size_t)(((n0 >> 4) + nt) * 8 + kk) * 512 + lane * 8);
            acc[nt] = __builtin_amdgcn_mfma_f32_16x16x32_bf16(af, bf, acc[nt], 0, 0, 0);
        }
    }
    int o_base = o0 + w * 16 + quad * 4;
    #pragma unroll
    for (int nt = 0; nt < 4; ++nt) {
        int n = n0 + nt * 16 + l15;
        #pragma unroll
        for (int r = 0; r < 4; ++r) {
            int o = o_base + r;
            size_t idx = ((size_t)(b * CC + o)) * NN + n;
            out[idx] = acc[nt][r] + b_proj[o] + x[idx];
        }
    }
}

extern "C" void kernel_launch(void* const* d_in, const int* in_sizes, int n_in,
                              void* d_out, int out_size, void* d_ws, size_t ws_size,
                              hipStream_t stream) {
    const float* x      = (const float*)d_in[0];
    const float* gamma  = (const float*)d_in[1];
    const float* beta   = (const float*)d_in[2];
    const float* w_qkv  = (const float*)d_in[3];
    const float* w_proj = (const float*)d_in[4];
    const float* b_proj = (const float*)d_in[5];
    float* out = (float*)d_out;

    char* p = (char*)d_ws;
    float* stats = (float*)p; p += 256;
    float* gsum  = (float*)p; p += 256;
    float* biasq = (float*)p; p += (size_t)BB * 768 * sizeof(float);
    u16* wqf = (u16*)p; p += (size_t)BB * 768 * CC * 2;
    u16* wpf = (u16*)p; p += (size_t)CC * CC * 2;
    u16* xtf = (u16*)p; p += (size_t)BB * NN * CC * 2;
    u8* qtf8 = (u8*)p; p += (size_t)BB * NN * CC;
    u8* ktf8 = (u8*)p; p += (size_t)BB * NN * CC;
    u8* vvf8 = (u8*)p; p += (size_t)BB * NN * CC;
    u16* otf = (u16*)p; p += (size_t)BB * NN * CC * 2;
    u16* po = (u16*)p; p += (size_t)SPLITS * BB * NN * CC * 2;
    float* lp = (float*)p; p += (size_t)SPLITS * BB * NN * sizeof(float);
    (void)ws_size; (void)in_sizes; (void)n_in; (void)out_size;

    (void)hipMemsetAsync(gsum, 0, BB * GG * 2 * sizeof(float), stream);
    transpose_x<<<dim3(NN / 64, CC / 64, BB), 256, 0, stream>>>(x, xtf, gsum);
    gn_finalize<<<1, 64, 0, stream>>>(gsum, stats);
    fold_w<<<dim3(768, BB), 256, 0, stream>>>(w_qkv, w_proj, gamma, beta, stats, wqf, biasq, wpf);
    qkv_gemm<<<dim3(NN / 64, 6, BB), 256, 0, stream>>>(wqf, biasq, xtf, qtf8, ktf8, vvf8);
    flash<<<(NN / 128) * SPLITS * BB, 512, 0, stream>>>(qtf8, ktf8, vvf8, po, lp);
    combine<<<(BB * NN * CC / 32) / 256, 256, 0, stream>>>(po, lp, otf);
    proj<<<dim3(NN / 64, CC / 64, BB), 256, 0, stream>>>(wpf, b_proj, otf, x, out);
}

// Round 11
// 172.370 us; speedup vs baseline: 1.6349x; 1.0734x over previous
//
#include <hip/hip_runtime.h>
#include <hip/hip_bf16.h>

#define BB 4
#define CC 256
#define NN 4096
#define GG 8
#define SPLITS 4
#define TKV 64
#define ITERS (NN / SPLITS / TKV)

typedef unsigned char u8;
typedef unsigned short u16;
typedef unsigned int u32;
typedef __bf16 b16x8 __attribute__((ext_vector_type(8)));
typedef float f32x4 __attribute__((ext_vector_type(4)));
typedef u32 u32x4 __attribute__((ext_vector_type(4)));
typedef u32 u32x2 __attribute__((ext_vector_type(2)));
typedef u16 u16x4 __attribute__((ext_vector_type(4)));

// softmax: P' = exp2(S_raw * QS - FMAX); QS = C^-0.5 * log2(e). FMAX=8 keeps
// P' inside e4m3's normal range. l,O scale-invariant.
#define QS 0.09016844005556021f
#define FMAX 8.0f

// bf16 fragment chunk (512 u16): elem(row,col32) = (quad(col32>>3)*16+row)*8+(col32&7)
// fp8 superchunk (1024 B, 16 rows x 64 cols): two 8B frags per lane:
//   addr(row,col) = ((col&31)>>3)*256 + row*16 + ((col>>5)&1)*8 + (col&7)
// fp8 V superchunk (1024 B, 32 c x 32 kv):
//   addr(c,kv) = ((kv&31)>>3)*256 + (c&15)*16 + ((c>>4)&1)*8 + (kv&7)

__device__ __forceinline__ u16 f2bf(float f) {
    u32 u = __builtin_bit_cast(u32, f);
    u = (u + 0x7FFFu + ((u >> 16) & 1u)) >> 16;
    return (u16)u;
}

__device__ __forceinline__ float bf2f(u16 h) {
    return __builtin_bit_cast(float, (u32)h << 16);
}

__device__ __forceinline__ u32 pack_bf2(float a, float b) {
    float2 f; f.x = a; f.y = b;
    __hip_bfloat162 h = __float22bfloat162_rn(f);
    u32 r;
    __builtin_memcpy(&r, &h, 4);
    return r;
}

__device__ __forceinline__ float exp2_raw(float x) {
#if __has_builtin(__builtin_amdgcn_exp2f)
    return __builtin_amdgcn_exp2f(x);
#else
    float r;
    asm("v_exp_f32 %0, %1" : "=v"(r) : "v"(x));
    return r;
#endif
}

__device__ __forceinline__ b16x8 ldfrag(const u16* p) {
    u32x4 v = *reinterpret_cast<const u32x4*>(p);
    return __builtin_bit_cast(b16x8, v);
}

__device__ __forceinline__ int pk_fp8x4(float a, float b, float c, float d) {
    int r = __builtin_amdgcn_cvt_pk_fp8_f32(a, b, 0, false);
    r = __builtin_amdgcn_cvt_pk_fp8_f32(c, d, r, true);
    return r;
}

__device__ __forceinline__ long as_long(u32x2 v) { return __builtin_bit_cast(long, v); }

typedef __attribute__((address_space(1))) const unsigned int* gas_p;
typedef __attribute__((address_space(3))) unsigned int* las_p;

__device__ __forceinline__ void g2l(const u8* g, u8* l) {
    __builtin_amdgcn_global_load_lds((gas_p)g, (las_p)l, 16, 0, 0);
}

__device__ __forceinline__ void g2l16(const u16* g, u16* l) {
    __builtin_amdgcn_global_load_lds((gas_p)g, (las_p)l, 16, 0, 0);
}

// ------- 2. Fold GN into QKV weights (stats inlined from gsum) + frag-major w_proj -------
__global__ void fold_w(const float* __restrict__ w_qkv, const float* __restrict__ w_proj,
                       const float* __restrict__ gamma, const float* __restrict__ beta,
                       const float* __restrict__ gsum,
                       u16* __restrict__ wqf, float* __restrict__ biasq,
                       u16* __restrict__ wpf) {
    int o = blockIdx.x;        // 0..767
    int b = blockIdx.y;        // 0..3
    int c = threadIdx.x;       // 0..255
    int g = c >> 5;
    const float inv = 1.f / ((CC / GG) * NN);
    float s  = gsum[(b * GG + g) * 2];
    float ss = gsum[(b * GG + g) * 2 + 1];
    float mu = s * inv;
    float rstd = rsqrtf(ss * inv - mu * mu + 1e-5f);
    float a  = gamma[c] * rstd;
    float bb = beta[c] - mu * a;
    float w = w_qkv[o * CC + c];
    size_t fe = ((size_t)((o >> 4) * 8 + (c >> 5)) * 64 + ((c & 31) >> 3) * 16 + (o & 15)) * 8 + (c & 7);
    wqf[(size_t)b * 768 * CC + fe] = f2bf(w * a);
    float part = w * bb;
    #pragma unroll
    for (int off = 32; off; off >>= 1) part += __shfl_down(part, off, 64);
    __shared__ float red[4];
    if ((threadIdx.x & 63) == 0) red[threadIdx.x >> 6] = part;
    __syncthreads();
    if (threadIdx.x == 0) biasq[b * 768 + o] = red[0] + red[1] + red[2] + red[3];
    if (b == 0 && o < CC) {
        float wp = w_proj[o * CC + c];
        wpf[fe] = f2bf(wp);
    }
}

// ---- 3. x [B][C][N] fp32 -> xt_frag bf16 (float4 loads); fused GN partial sums ----
__global__ void transpose_x(const float* __restrict__ x, u16* __restrict__ xtf,
                            float* __restrict__ gsum) {
    __shared__ float tile[64][65];
    __shared__ float red[4][4];
    int n0 = blockIdx.x * 64, c0 = blockIdx.y * 64, b = blockIdx.z;
    int t = threadIdx.x;
    int c4 = (t & 15) * 4;        // col base within 64-n tile
    int r0 = t >> 4;              // 0..15
    const float* xp = x + (size_t)b * CC * NN;
    float s0 = 0.f, ss0 = 0.f, s1 = 0.f, ss1 = 0.f;
    #pragma unroll
    for (int i = 0; i < 4; ++i) {
        int row = i * 16 + r0;
        float4 v = *reinterpret_cast<const float4*>(&xp[(size_t)(c0 + row) * NN + n0 + c4]);
        tile[row][c4 + 0] = v.x; tile[row][c4 + 1] = v.y;
        tile[row][c4 + 2] = v.z; tile[row][c4 + 3] = v.w;
        float s = v.x + v.y + v.z + v.w;
        float q = v.x * v.x + v.y * v.y + v.z * v.z + v.w * v.w;
        if (i < 2) { s0 += s; ss0 += q; } else { s1 += s; ss1 += q; }
    }
    #pragma unroll
    for (int off = 32; off; off >>= 1) {
        s0 += __shfl_down(s0, off, 64); ss0 += __shfl_down(ss0, off, 64);
        s1 += __shfl_down(s1, off, 64); ss1 += __shfl_down(ss1, off, 64);
    }
    int wid = t >> 6;
    if ((t & 63) == 0) { red[wid][0] = s0; red[wid][1] = ss0; red[wid][2] = s1; red[wid][3] = ss1; }
    __syncthreads();
    if (t < 2) {
        float s  = red[0][t * 2] + red[1][t * 2] + red[2][t * 2] + red[3][t * 2];
        float ss = red[0][t * 2 + 1] + red[1][t * 2 + 1] + red[2][t * 2 + 1] + red[3][t * 2 + 1];
        int g = (c0 >> 5) + t;
        atomicAdd(&gsum[(b * GG + g) * 2], s);
        atomicAdd(&gsum[(b * GG + g) * 2 + 1], ss);
    }
    int nl = t >> 2;
    int cbq = t & 3;
    int l15 = nl & 15;
    int ntile = (n0 >> 4) + (nl >> 4);
    int kk = (c0 >> 5) + (cbq >> 1);
    u16* ob = xtf + (size_t)b * NN * CC;
    #pragma unroll
    for (int g = 0; g < 4; ++g) {
        int quad = (cbq & 1) * 2 + (g >> 1);
        int j0 = (g & 1) * 4;
        u16x4 v;
        v.x = f2bf(tile[cbq * 16 + g * 4 + 0][nl]);
        v.y = f2bf(tile[cbq * 16 + g * 4 + 1][nl]);
        v.z = f2bf(tile[cbq * 16 + g * 4 + 2][nl]);
        v.w = f2bf(tile[cbq * 16 + g * 4 + 3][nl]);
        *reinterpret_cast<u16x4*>(ob + ((size_t)(ntile * 8 + kk) * 64 + quad * 16 + l15) * 8 + j0) = v;
    }
}

// ------- 4. QKV GEMM: LDS-staged B-tile, 128 o-rows/block -> fp8 q/k/v superchunks -------
__global__ void __launch_bounds__(256) qkv_gemm(const u16* __restrict__ wqf,
                                                const float* __restrict__ biasq,
                                                const u16* __restrict__ xtf,
                                                u8* __restrict__ qtf, u8* __restrict__ ktf,
                                                u8* __restrict__ vvf) {
    __shared__ u16 bx[16384];     // 64 n x 256 c bf16 frag tile, 32 KB contiguous
    int b = blockIdx.z;
    int o0 = blockIdx.y * 128;    // 0,128,...,640 — never spans Q/K/V boundary
    int n0 = blockIdx.x * 64;
    int lane = threadIdx.x & 63, w = threadIdx.x >> 6;
    int l15 = lane & 15, quad = lane >> 4;
    const u16* Bg = xtf + (size_t)b * NN * CC + (size_t)n0 * 256;
    #pragma unroll
    for (int j = 0; j < 8; ++j) {
        int c = w * 8 + j;
        g2l16(Bg + (size_t)c * 512 + lane * 8, bx + (size_t)c * 512 + lane * 8);
    }
    __syncthreads();

    const u16* A = wqf + (size_t)b * 768 * CC;
    f32x4 acc[2][4] = {};
    #pragma unroll
    for (int kk = 0; kk < 8; ++kk) {
        b16x8 af[2];
        #pragma unroll
        for (int t = 0; t < 2; ++t) {
            int otile = (o0 >> 4) + w * 2 + t;
            af[t] = ldfrag(A + (size_t)(otile * 8 + kk) * 512 + lane * 8);
        }
        #pragma unroll
        for (int nt = 0; nt < 4; ++nt) {
            b16x8 bf = ldfrag(bx + (size_t)(nt * 8 + kk) * 512 + lane * 8);
            acc[0][nt] = __builtin_amdgcn_mfma_f32_16x16x32_bf16(af[0], bf, acc[0][nt], 0, 0, 0);
            acc[1][nt] = __builtin_amdgcn_mfma_f32_16x16x32_bf16(af[1], bf, acc[1][nt], 0, 0, 0);
        }
    }
    #pragma unroll
    for (int t = 0; t < 2; ++t) {
        int o_base = o0 + (w * 2 + t) * 16 + quad * 4;
        float bias[4];
        #pragma unroll
        for (int r = 0; r < 4; ++r) bias[r] = biasq[b * 768 + o_base + r];
        if (o0 < 512) {
            int oloc = (o0 < 256) ? o_base : (o_base - 256);
            u8* dst = ((o0 < 256) ? qtf : ktf) + (size_t)b * NN * CC;
            #pragma unroll
            for (int nt = 0; nt < 4; ++nt) {
                int n = n0 + nt * 16 + l15;
                int pk = pk_fp8x4(acc[t][nt][0] + bias[0], acc[t][nt][1] + bias[1],
                                  acc[t][nt][2] + bias[2], acc[t][nt][3] + bias[3]);
                size_t addr = (size_t)((n >> 4) * 4 + (oloc >> 6)) * 1024
                            + ((oloc & 31) >> 3) * 256 + (n & 15) * 16
                            + ((oloc >> 5) & 1) * 8 + (oloc & 7);
                *reinterpret_cast<u32*>(dst + addr) = (u32)pk;
            }
        } else {
            int cb = o_base - 512;
            u8* dst = vvf + (size_t)b * NN * CC;
            #pragma unroll
            for (int nt = 0; nt < 4; ++nt) {
                int kv = n0 + nt * 16 + l15;
                int pk = pk_fp8x4(acc[t][nt][0] + bias[0], acc[t][nt][1] + bias[1],
                                  acc[t][nt][2] + bias[2], acc[t][nt][3] + bias[3]);
                size_t base = (size_t)((kv >> 5) * 8 + (cb >> 5)) * 1024
                            + ((kv & 31) >> 3) * 256 + ((cb >> 4) & 1) * 8 + (kv & 7);
                #pragma unroll
                for (int r = 0; r < 4; ++r)
                    dst[base + ((cb & 15) + r) * 16] = (u8)(pk >> (r * 8));
            }
        }
    }
}

// ----- 5. Flash: all-fp8, 512-thread blocks, TKV=64, double-buffered (unchanged R10) -----
__global__ void __launch_bounds__(512, 4) flash(const u8* __restrict__ qtf,
                                                const u8* __restrict__ ktf,
                                                const u8* __restrict__ vvf,
                                                u16* __restrict__ po,
                                                float* __restrict__ lp) {
    __shared__ u8 kbuf[2][16384];
    __shared__ u8 vbuf[2][16384];
    __shared__ u8 pbuf[8][16 * 72];
    int lin = blockIdx.x;
    int chunk = lin & 15;
    int nblk = lin >> 4;                  // 0..31
    int b = chunk >> 2, sp = chunk & 3;
    int lane = threadIdx.x & 63, w = threadIdx.x >> 6;   // w 0..7
    int l15 = lane & 15, quad = lane >> 4;
    int ntile = nblk * 8 + w;             // this wave's 16 q rows (0..255)
    const u8* kb8 = ktf + (size_t)b * NN * CC;
    const u8* vb8 = vvf + (size_t)b * NN * CC;
    u8* pw = &pbuf[w][0];

    const u32x2 ones2 = {0x38383838u, 0x38383838u};   // e4m3 1.0 x8
    const long ones8 = as_long(ones2);

    u32x4 aq[4];
    const u8* qb = qtf + (size_t)b * NN * CC + (size_t)ntile * 4096;
    #pragma unroll
    for (int s = 0; s < 4; ++s)
        aq[s] = *reinterpret_cast<const u32x4*>(qb + s * 1024 + lane * 16);

    f32x4 acco[16] = {};
    f32x4 acco_l = {};

    const int m_beg = sp * (NN / SPLITS);

    auto stage = [&](int buf, int m0) {
        const u8* ks = kb8 + ((size_t)m0 << 8);
        const u8* vs = vb8 + ((size_t)m0 << 8);
        #pragma unroll
        for (int j = 0; j < 4; ++j) {
            int idx = w * 4 + j;          // 0..31
            if (idx < 16) g2l(ks + idx * 1024 + lane * 16, &kbuf[buf][idx * 1024]);
            else          g2l(vs + (idx - 16) * 1024 + lane * 16, &vbuf[buf][(idx - 16) * 1024]);
        }
    };

    stage(0, m_beg);
    __syncthreads();
    for (int it = 0; it < ITERS; ++it) {
        int cur = it & 1;
        if (it + 1 < ITERS) stage(cur ^ 1, m_beg + (it + 1) * TKV);
        const u8* kc = &kbuf[cur][0];
        const u8* vc = &vbuf[cur][0];
        f32x4 accs[4] = {};
        #pragma unroll
        for (int s = 0; s < 4; ++s) {     // c64 index
            long alo = as_long(u32x2{aq[s].x, aq[s].y});
            long ahi = as_long(u32x2{aq[s].z, aq[s].w});
            #pragma unroll
            for (int m = 0; m < 4; ++m) {
                u32x4 kf = *reinterpret_cast<const u32x4*>(kc + (size_t)(m * 4 + s) * 1024 + lane * 16);
                accs[m] = __builtin_amdgcn_mfma_f32_16x16x32_fp8_fp8(
                    alo, as_long(u32x2{kf.x, kf.y}), accs[m], 0, 0, 0);
                accs[m] = __builtin_amdgcn_mfma_f32_16x16x32_fp8_fp8(
                    ahi, as_long(u32x2{kf.z, kf.w}), accs[m], 0, 0, 0);
            }
        }
        #pragma unroll
        for (int m = 0; m < 4; ++m) {
            float e0 = exp2_raw(fmaf(accs[m][0], QS, -FMAX));
            float e1 = exp2_raw(fmaf(accs[m][1], QS, -FMAX));
            float e2 = exp2_raw(fmaf(accs[m][2], QS, -FMAX));
            float e3 = exp2_raw(fmaf(accs[m][3], QS, -FMAX));
            int p01 = __builtin_amdgcn_cvt_pk_fp8_f32(e0, e1, 0, false);
            int p23 = __builtin_amdgcn_cvt_pk_fp8_f32(e2, e3, 0, false);
            u8* pr = pw + m * 16 + l15;
            pr[(quad * 4 + 0) * 72] = (u8)p01;
            pr[(quad * 4 + 1) * 72] = (u8)(p01 >> 8);
            pr[(quad * 4 + 2) * 72] = (u8)p23;
            pr[(quad * 4 + 3) * 72] = (u8)(p23 >> 8);
        }
        asm volatile("s_waitcnt lgkmcnt(0)" ::: "memory");
        long ap0 = as_long(*reinterpret_cast<const u32x2*>(pw + l15 * 72 + quad * 8));
        long ap1 = as_long(*reinterpret_cast<const u32x2*>(pw + l15 * 72 + 32 + quad * 8));
        acco_l = __builtin_amdgcn_mfma_f32_16x16x32_fp8_fp8(ap0, ones8, acco_l, 0, 0, 0);
        acco_l = __builtin_amdgcn_mfma_f32_16x16x32_fp8_fp8(ap1, ones8, acco_l, 0, 0, 0);
        #pragma unroll
        for (int c2 = 0; c2 < 8; ++c2) {
            u32x4 vf0 = *reinterpret_cast<const u32x4*>(vc + (size_t)c2 * 1024 + lane * 16);
            u32x4 vf1 = *reinterpret_cast<const u32x4*>(vc + (size_t)(8 + c2) * 1024 + lane * 16);
            acco[c2 * 2]     = __builtin_amdgcn_mfma_f32_16x16x32_fp8_fp8(
                ap0, as_long(u32x2{vf0.x, vf0.y}), acco[c2 * 2], 0, 0, 0);
            acco[c2 * 2 + 1] = __builtin_amdgcn_mfma_f32_16x16x32_fp8_fp8(
                ap0, as_long(u32x2{vf0.z, vf0.w}), acco[c2 * 2 + 1], 0, 0, 0);
            acco[c2 * 2]     = __builtin_amdgcn_mfma_f32_16x16x32_fp8_fp8(
                ap1, as_long(u32x2{vf1.x, vf1.y}), acco[c2 * 2], 0, 0, 0);
            acco[c2 * 2 + 1] = __builtin_amdgcn_mfma_f32_16x16x32_fp8_fp8(
                ap1, as_long(u32x2{vf1.z, vf1.w}), acco[c2 * 2 + 1], 0, 0, 0);
        }
        __syncthreads();
    }
    u16* pochunk = po + ((size_t)(sp * BB + b) * 256 + ntile) * 4096;
    #pragma unroll
    for (int ct = 0; ct < 16; ++ct) {
        u32x2 st;
        st.x = pack_bf2(acco[ct][0], acco[ct][1]);
        st.y = pack_bf2(acco[ct][2], acco[ct][3]);
        *reinterpret_cast<u32x2*>(pochunk + (size_t)(ct * 64 + quad * 16 + l15) * 4) = st;
    }
    if (l15 == 0) {
        size_t lbase = (size_t)(sp * BB + b) * NN + ntile * 16;
        #pragma unroll
        for (int r = 0; r < 4; ++r) lp[lbase + quad * 4 + r] = acco_l[r];
    }
}

// ------- 6. Fused proj: combine po/lp -> LDS bf16 frags, GEMM, + bias + residual -------
__global__ void __launch_bounds__(512) proj(const u16* __restrict__ wpf,
                                            const float* __restrict__ b_proj,
                                            const u16* __restrict__ po,
                                            const float* __restrict__ lp,
                                            const float* __restrict__ x,
                                            float* __restrict__ out) {
    __shared__ u16 bO[16384];      // 64 n x 256 c bf16 frag-major (local ntile-major)
    int b = blockIdx.y, n0 = blockIdx.x * 64;
    int t = threadIdx.x;
    // phase 1: combine 4 splits of po into bO (same math/order as old combine kernel)
    {
        int cg = t & 31, quad = (t >> 5) & 3, ntl = t >> 7;   // ntl 0..3
        int nb = (n0 >> 4) + ntl;
        float acc[4][8] = {};
        float lsum[4] = {};
        #pragma unroll
        for (int s = 0; s < SPLITS; ++s) {
            const u16* src = po + (((size_t)(s * BB + b) * 256 + nb) * 4096)
                           + ((cg >> 1) * 256 + quad * 64 + (cg & 1) * 32);
            u16 s16[32];
            #pragma unroll
            for (int q = 0; q < 4; ++q)
                *reinterpret_cast<u32x4*>(&s16[q * 8]) = *reinterpret_cast<const u32x4*>(src + q * 8);
            #pragma unroll
            for (int r = 0; r < 4; ++r)
                #pragma unroll
                for (int j = 0; j < 8; ++j)
                    acc[r][j] += bf2f(s16[j * 4 + r]);
            #pragma unroll
            for (int r = 0; r < 4; ++r)
                lsum[r] += lp[(size_t)(s * BB + b) * NN + nb * 16 + quad * 4 + r];
        }
        #pragma unroll
        for (int r = 0; r < 4; ++r) {
            float inv = 1.f / lsum[r];
            u16 outv[8];
            #pragma unroll
            for (int j = 0; j < 8; ++j) outv[j] = f2bf(acc[r][j] * inv);
            size_t off = ((size_t)(ntl * 8 + (cg >> 2)) * 64 + (cg & 3) * 16 + quad * 4 + r) * 8;
            *reinterpret_cast<u32x4*>(bO + off) = *reinterpret_cast<const u32x4*>(outv);
        }
    }
    __syncthreads();
    // phase 2: GEMM — 8 waves x 2 o-tiles = full 256 outputs
    int lane = t & 63, w = t >> 6;
    int l15 = lane & 15, quad = lane >> 4;
    f32x4 acc2[2][4] = {};
    #pragma unroll
    for (int kk = 0; kk < 8; ++kk) {
        b16x8 af[2];
        #pragma unroll
        for (int tt = 0; tt < 2; ++tt) {
            int otile = w * 2 + tt;
            af[tt] = ldfrag(wpf + (size_t)(otile * 8 + kk) * 512 + lane * 8);
        }
        #pragma unroll
        for (int nt = 0; nt < 4; ++nt) {
            b16x8 bf = ldfrag(bO + (size_t)(nt * 8 + kk) * 512 + lane * 8);
            acc2[0][nt] = __builtin_amdgcn_mfma_f32_16x16x32_bf16(af[0], bf, acc2[0][nt], 0, 0, 0);
            acc2[1][nt] = __builtin_amdgcn_mfma_f32_16x16x32_bf16(af[1], bf, acc2[1][nt], 0, 0, 0);
        }
    }
    #pragma unroll
    for (int tt = 0; tt < 2; ++tt) {
        int o_base = (w * 2 + tt) * 16 + quad * 4;
        #pragma unroll
        for (int nt = 0; nt < 4; ++nt) {
            int n = n0 + nt * 16 + l15;
            #pragma unroll
            for (int r = 0; r < 4; ++r) {
                int o = o_base + r;
                size_t idx = ((size_t)(b * CC + o)) * NN + n;
                out[idx] = acc2[tt][nt][r] + b_proj[o] + x[idx];
            }
        }
    }
}

extern "C" void kernel_launch(void* const* d_in, const int* in_sizes, int n_in,
                              void* d_out, int out_size, void* d_ws, size_t ws_size,
                              hipStream_t stream) {
    const float* x      = (const float*)d_in[0];
    const float* gamma  = (const float*)d_in[1];
    const float* beta   = (const float*)d_in[2];
    const float* w_qkv  = (const float*)d_in[3];
    const float* w_proj = (const float*)d_in[4];
    const float* b_proj = (const float*)d_in[5];
    float* out = (float*)d_out;

    char* p = (char*)d_ws;
    float* gsum  = (float*)p; p += 256;
    float* biasq = (float*)p; p += (size_t)BB * 768 * sizeof(float);
    u16* wqf = (u16*)p; p += (size_t)BB * 768 * CC * 2;
    u16* wpf = (u16*)p; p += (size_t)CC * CC * 2;
    u16* xtf = (u16*)p; p += (size_t)BB * NN * CC * 2;
    u8* qtf8 = (u8*)p; p += (size_t)BB * NN * CC;
    u8* ktf8 = (u8*)p; p += (size_t)BB * NN * CC;
    u8* vvf8 = (u8*)p; p += (size_t)BB * NN * CC;
    u16* po = (u16*)p; p += (size_t)SPLITS * BB * NN * CC * 2;
    float* lp = (float*)p; p += (size_t)SPLITS * BB * NN * sizeof(float);
    (void)ws_size; (void)in_sizes; (void)n_in; (void)out_size;

    (void)hipMemsetAsync(gsum, 0, BB * GG * 2 * sizeof(float), stream);
    transpose_x<<<dim3(NN / 64, CC / 64, BB), 256, 0, stream>>>(x, xtf, gsum);
    fold_w<<<dim3(768, BB), 256, 0, stream>>>(w_qkv, w_proj, gamma, beta, gsum, wqf, biasq, wpf);
    qkv_gemm<<<dim3(NN / 64, 6, BB), 256, 0, stream>>>(wqf, biasq, xtf, qtf8, ktf8, vvf8);
    flash<<<(NN / 128) * SPLITS * BB, 512, 0, stream>>>(qtf8, ktf8, vvf8, po, lp);
    proj<<<dim3(NN / 64, BB), 512, 0, stream>>>(wpf, b_proj, po, lp, x, out);
}